// Round 15
// baseline (177.875 us; speedup 1.0000x reference)
//
#include <hip/hip_runtime.h>
#include <cstdint>

#define TB 16
#define TS 512
#define TD 512
#define TH 8
#define TDH 64
#define TSD (TS*TD)   // 262144

typedef __attribute__((ext_vector_type(8))) short s16x8;
typedef __attribute__((ext_vector_type(4))) float f32x4;
typedef unsigned short bfu;

// HW packed fp32->bf16 (RNE), gfx950
__device__ __forceinline__ unsigned cvt_pk(float lo, float hi) {
  unsigned r;
  asm("v_cvt_pk_bf16_f32 %0, %1, %2" : "=v"(r) : "v"(lo), "v"(hi));
  return r;
}
__device__ __forceinline__ unsigned short f2b(float f) {
  unsigned r;
  asm("v_cvt_pk_bf16_f32 %0, %1, %2" : "=v"(r) : "v"(f), "v"(f));
  return (unsigned short)r;
}
__device__ __forceinline__ float b2f(bfu h) {
  return __uint_as_float(((unsigned)h) << 16);
}

__device__ __forceinline__ void gll16(const void* g, void* l) {
  __builtin_amdgcn_global_load_lds((const __attribute__((address_space(1))) void*)g,
                                   (__attribute__((address_space(3))) void*)l, 16, 0, 0);
}

__device__ __forceinline__ f32x4 MFMA16(s16x8 a, s16x8 b, f32x4 c) {
  return __builtin_amdgcn_mfma_f32_16x16x32_bf16(a, b, c, 0, 0, 0);
}

// ---------------- K0: fused cast x (fp32->bf16) + build W^T bf16 [1536][512] ----------------
__global__ __launch_bounds__(256) void k_prep(const float* __restrict__ x, uint2* __restrict__ xb,
                                              const float* __restrict__ WQ, const float* __restrict__ WK,
                                              const float* __restrict__ WV, bfu* __restrict__ wt) {
  int t = threadIdx.x;
  if (blockIdx.x < 4096) {
    int i = blockIdx.x * 256 + t;
    float4 v = ((const float4*)x)[i];
    uint2 o; o.x = cvt_pk(v.x, v.y); o.y = cvt_pk(v.z, v.w);
    xb[i] = o;
    return;
  }
  __shared__ float tile[64][65];
  int bid = blockIdx.x - 4096;
  int bk = bid & 7;
  int bn = bid >> 3;
  const float* W = bn < 8 ? WQ : (bn < 16 ? WK : WV);
  int ncol0 = (bn & 7) * 64;
  int tx = t & 63, ty = t >> 6;
  #pragma unroll
  for (int i = 0; i < 16; ++i) {
    int kl = i * 4 + ty;
    tile[kl][tx] = W[(size_t)(bk * 64 + kl) * 512 + ncol0 + tx];
  }
  __syncthreads();
  #pragma unroll
  for (int i = 0; i < 16; ++i) {
    int nl = i * 4 + ty;
    wt[(size_t)(bn * 64 + nl) * 512 + bk * 64 + tx] = f2b(tile[tx][nl]);
  }
}

// ---------------- K1: QKV GEMM — round-7 proven: 256 thr, 4 waves, dbuf + swizzle ----------------
__global__ __launch_bounds__(256) void k_qkv(const bfu* __restrict__ xb, const bfu* __restrict__ wt,
                                             bfu* __restrict__ qb, bfu* __restrict__ kb, bfu* __restrict__ vtb) {
  __shared__ __align__(16) bfu At[2][128 * 32];
  __shared__ __align__(16) bfu Bt[2][128 * 32];
  int t = threadIdx.x, lane = t & 63, w = t >> 6;
  int wr = w >> 1, wc = w & 1;
  int m0 = blockIdx.x * 128, n0 = blockIdx.y * 128;
  int fr = lane & 15, hi = lane >> 4;
  int l4r = lane >> 2, l4c = lane & 3;
  f32x4 acc[4][4] = {};

#define QKV_STAGE(BUF, K0) { \
    _Pragma("unroll") \
    for (int i = 0; i < 2; ++i) { \
      int row = i * 64 + w * 16 + l4r; \
      int cs = l4c ^ (l4r & 3); \
      gll16(xb + (size_t)(m0 + row) * TD + (K0) + cs * 8, (char*)At[BUF] + (i * 256 + w * 64) * 16); \
      gll16(wt + (size_t)(n0 + row) * TD + (K0) + cs * 8, (char*)Bt[BUF] + (i * 256 + w * 64) * 16); \
    } }

#define QKV_COMP(BUF) { \
    s16x8 a[4], bb[4]; \
    int ca = (hi ^ (fr & 3)) * 8; \
    _Pragma("unroll") \
    for (int m = 0; m < 4; ++m) a[m]  = *(const s16x8*)&At[BUF][(wr * 64 + m * 16 + fr) * 32 + ca]; \
    _Pragma("unroll") \
    for (int n = 0; n < 4; ++n) bb[n] = *(const s16x8*)&Bt[BUF][(wc * 64 + n * 16 + fr) * 32 + ca]; \
    _Pragma("unroll") \
    for (int m = 0; m < 4; ++m) \
      _Pragma("unroll") \
      for (int n = 0; n < 4; ++n) \
        acc[m][n] = MFMA16(a[m], bb[n], acc[m][n]); }

  QKV_STAGE(0, 0)
  __syncthreads();
  for (int k = 0; k < 16; ++k) {
    int cur = k & 1;
    if (k < 15) QKV_STAGE(cur ^ 1, (k + 1) * 32)
    QKV_COMP(cur)
    __syncthreads();
  }
#undef QKV_STAGE
#undef QKV_COMP

  #pragma unroll
  for (int m = 0; m < 4; ++m) {
    int grow = m0 + wr * 64 + m * 16 + hi * 4;
    #pragma unroll
    for (int n = 0; n < 4; ++n) {
      int gcol = n0 + wc * 64 + n * 16 + fr;
      if (gcol < 512) {
        #pragma unroll
        for (int r = 0; r < 4; ++r) qb[(size_t)(grow + r) * TD + gcol] = f2b(acc[m][n][r]);
      } else if (gcol < 1024) {
        int c = gcol - 512;
        #pragma unroll
        for (int r = 0; r < 4; ++r) kb[(size_t)(grow + r) * TD + c] = f2b(acc[m][n][r]);
      } else {
        int c = gcol - 1024;
        int hh = c >> 6, dc = c & 63;
        int b_ = grow >> 9, s = grow & 511;
        ushort4 pk;
        pk.x = f2b(acc[m][n][0]); pk.y = f2b(acc[m][n][1]);
        pk.z = f2b(acc[m][n][2]); pk.w = f2b(acc[m][n][3]);
        *(ushort4*)&vtb[((size_t)((b_ * TH + hh) * TDH + dc) << 9) + s] = pk;
      }
    }
  }
}

// ---------------- K2: attention — Q in regs, Ps ALIASES Ks => 32KB LDS, 5 blocks/CU ----------------
// Within each kt: Ks fully consumed by QK^T before P is produced; Ks restaged next kt anyway.
// One buffer serves both (K-layout then P-layout); extra barrier post-QK^T guards the alias.
__global__ __launch_bounds__(256) void k_attn(const bfu* __restrict__ qb, const bfu* __restrict__ kb,
                                              const bfu* __restrict__ vtb, const bfu* __restrict__ xb,
                                              float* __restrict__ ao) {
  __shared__ __align__(16) bfu KPs[128 * 64];   // Ks [128k][64d] / Ps [64q][128k] alias (16KB)
  __shared__ __align__(16) bfu Vs[64 * 128];    // [dh][keys] (16KB)
  int t = threadIdx.x, lane = t & 63, w = t >> 6;
  int qt = blockIdx.x, h = blockIdx.y, b = blockIdx.z;
  size_t qrow0 = (size_t)b * TS + qt * 64;
  int fr = lane & 15, hi = lane >> 4;
  int l8r = lane >> 3, l8c = lane & 7;
  int l16r = lane >> 4, l16c = lane & 15;

#define K_STAGE(KT) { \
    _Pragma("unroll") \
    for (int i = 0; i < 4; ++i) { \
      int row = i * 32 + w * 8 + l8r; \
      int cs = l8c ^ (l8r & 7); \
      gll16(kb + ((size_t)b * TS + (KT) * 128 + row) * TD + h * TDH + cs * 8, \
            (char*)KPs + (i * 256 + w * 64) * 16); \
    } }
#define V_STAGE(KT) { \
    _Pragma("unroll") \
    for (int i = 0; i < 4; ++i) { \
      int row = i * 16 + w * 4 + l16r; \
      int cs = l16c ^ (row & 7); \
      gll16(vtb + ((size_t)(b * TH + h) * TDH + row) * TS + (KT) * 128 + cs * 8, \
            (char*)Vs + (i * 256 + w * 64) * 16); \
    } }

  int qrow = w * 16 + fr;
  // Q fragments: loop-invariant, direct global->reg (qb is L2-hot)
  const bfu* qp = qb + (qrow0 + qrow) * TD + h * TDH;
  s16x8 aq0 = *(const s16x8*)(qp + hi * 8);
  s16x8 aq1 = *(const s16x8*)(qp + 32 + hi * 8);

  K_STAGE(0)
  V_STAGE(0)
  __syncthreads();

  int r7 = fr & 7;
  f32x4 acc_o[4] = {};
  for (int kt = 0; kt < 4; ++kt) {
    f32x4 sc[8];
    #pragma unroll
    for (int kj = 0; kj < 8; ++kj) {
      int krow = kj * 16 + fr;
      s16x8 b0 = *(const s16x8*)&KPs[krow * 64 + ((hi ^ r7) * 8)];
      s16x8 b1 = *(const s16x8*)&KPs[krow * 64 + (((4 + hi) ^ r7) * 8)];
      f32x4 c = {};
      c = MFMA16(aq0, b0, c);
      c = MFMA16(aq1, b1, c);
      sc[kj] = c;
    }
    __syncthreads();   // all waves' K reads done before P overwrites the alias
    #pragma unroll
    for (int kj = 0; kj < 8; ++kj) {
      #pragma unroll
      for (int r = 0; r < 4; ++r) {
        float v = sc[kj][r] * 0.125f;
        float p = v / (1.f + __expf(-v));
        int prow = w * 16 + hi * 4 + r;
        int c8 = (kj * 2 + (fr >> 3)) ^ (prow & 7);
        KPs[prow * 128 + c8 * 8 + (fr & 7)] = f2b(p);
      }
    }
    // P rows wave-private: same-wave LDS RAW covered by lgkmcnt; no barrier.
    #pragma unroll
    for (int ks = 0; ks < 4; ++ks) {
      s16x8 pa = *(const s16x8*)&KPs[qrow * 128 + (((ks * 4 + hi) ^ r7) * 8)];
      #pragma unroll
      for (int dn = 0; dn < 4; ++dn) {
        s16x8 vb = *(const s16x8*)&Vs[(dn * 16 + fr) * 128 + (((ks * 4 + hi) ^ r7) * 8)];
        acc_o[dn] = MFMA16(pa, vb, acc_o[dn]);
      }
    }
    __syncthreads();   // PV reads done before restage overwrites KPs/Vs
    if (kt < 3) {
      K_STAGE(kt + 1)
      V_STAGE(kt + 1)
      __syncthreads();
    }
  }
#undef K_STAGE
#undef V_STAGE
  #pragma unroll
  for (int dn = 0; dn < 4; ++dn) {
    int col = h * TDH + dn * 16 + fr;
    #pragma unroll
    for (int r = 0; r < 4; ++r) {
      size_t row = qrow0 + w * 16 + hi * 4 + r;
      ao[row * TD + col] = acc_o[dn][r] + b2f(xb[row * TD + col]);
    }
  }
}

// ---------------- K3: LayerNorm — wave-per-row, no barriers, coalesced float4 ----------------
__global__ __launch_bounds__(256) void k_ln(const float* __restrict__ a, const float* __restrict__ wgt,
                                            const float* __restrict__ bias, bfu* __restrict__ o) {
  int t = threadIdx.x, lane = t & 63, w = t >> 6;
  int row = blockIdx.x * 4 + w;
  const float4* rp = (const float4*)(a + (size_t)row * TD);
  float4 v0 = rp[lane];
  float4 v1 = rp[64 + lane];
  float s = v0.x + v0.y + v0.z + v0.w + v1.x + v1.y + v1.z + v1.w;
  #pragma unroll
  for (int off = 1; off < 64; off <<= 1) s += __shfl_xor(s, off);
  float mean = s * (1.f / 512.f);
  float4 d0, d1;
  d0.x = v0.x - mean; d0.y = v0.y - mean; d0.z = v0.z - mean; d0.w = v0.w - mean;
  d1.x = v1.x - mean; d1.y = v1.y - mean; d1.z = v1.z - mean; d1.w = v1.w - mean;
  float q = d0.x * d0.x + d0.y * d0.y + d0.z * d0.z + d0.w * d0.w +
            d1.x * d1.x + d1.y * d1.y + d1.z * d1.z + d1.w * d1.w;
  #pragma unroll
  for (int off = 1; off < 64; off <<= 1) q += __shfl_xor(q, off);
  float inv = rsqrtf(q * (1.f / 512.f) + 1e-12f);
  float4 g0 = ((const float4*)wgt)[lane],  g1 = ((const float4*)wgt)[64 + lane];
  float4 b0 = ((const float4*)bias)[lane], b1 = ((const float4*)bias)[64 + lane];
  uint2 o0, o1;
  o0.x = cvt_pk(fmaf(d0.x * inv, g0.x, b0.x), fmaf(d0.y * inv, g0.y, b0.y));
  o0.y = cvt_pk(fmaf(d0.z * inv, g0.z, b0.z), fmaf(d0.w * inv, g0.w, b0.w));
  o1.x = cvt_pk(fmaf(d1.x * inv, g1.x, b1.x), fmaf(d1.y * inv, g1.y, b1.y));
  o1.y = cvt_pk(fmaf(d1.z * inv, g1.z, b1.z), fmaf(d1.w * inv, g1.w, b1.w));
  uint2* op = (uint2*)(o + (size_t)row * TD);
  op[lane] = o0;
  op[64 + lane] = o1;
}

// ---------------- K4: final linear via MFMA — round-7 proven (KC=2048) ----------------
__global__ __launch_bounds__(256) void k_lin_mfma(const bfu* __restrict__ lno, const float* __restrict__ wl,
                                                  float* __restrict__ part) {
  __shared__ __align__(16) bfu Wt[2][64 * 72];
  int t = threadIdx.x, lane = t & 63, w = t >> 6;
  int fr = lane & 15, hi = lane >> 4;
  int kc = blockIdx.x >> 3, nb = blockIdx.x & 7;
  int n0 = nb * 64;
  int nl = t & 63, kb = (t >> 6) * 16;
  int ks0 = kc * 2048;
  const float* wbase = wl + (size_t)(ks0 + kb) * 512 + n0 + nl;
  const bfu*   abase = lno + (size_t)fr * TSD + ks0 + hi * 8;
  f32x4 acc = {};
  float wreg[16];
  #pragma unroll
  for (int i = 0; i < 16; ++i) wreg[i] = __builtin_nontemporal_load(wbase + (size_t)i * 512);
  for (int s = 0; s < 32; ++s) {
    int cur = s & 1;
    unsigned pk[8];
    #pragma unroll
    for (int i = 0; i < 8; ++i) pk[i] = cvt_pk(wreg[2 * i], wreg[2 * i + 1]);
    *(uint4*)&Wt[cur][nl * 72 + kb]     = *(uint4*)&pk[0];
    *(uint4*)&Wt[cur][nl * 72 + kb + 8] = *(uint4*)&pk[4];
    if (s < 31) {
      const float* wp2 = wbase + (size_t)(s + 1) * 64 * 512;
      #pragma unroll
      for (int i = 0; i < 16; ++i) wreg[i] = __builtin_nontemporal_load(wp2 + (size_t)i * 512);
    }
    s16x8 a0 = *(const s16x8*)(abase + s * 64);
    s16x8 a1 = *(const s16x8*)(abase + s * 64 + 32);
    __syncthreads();   // write(cur) visible; 2-buffer rotation + own-lgkmcnt => race-free
    s16x8 b0 = *(const s16x8*)&Wt[cur][(w * 16 + fr) * 72 + hi * 8];
    s16x8 b1 = *(const s16x8*)&Wt[cur][(w * 16 + fr) * 72 + 32 + hi * 8];
    acc = MFMA16(a0, b0, acc);
    acc = MFMA16(a1, b1, acc);
  }
  #pragma unroll
  for (int r = 0; r < 4; ++r)
    part[(size_t)kc * 8192 + (hi * 4 + r) * 512 + n0 + w * 16 + fr] = acc[r];
}

// ---------------- K5: reduce 128 partials + bias + swish — 256 blocks, 1 LDS hop ----------------
__global__ __launch_bounds__(256) void k_lin_red(const float* __restrict__ part, const float* __restrict__ blin,
                                                 float* __restrict__ out) {
  __shared__ float sm[256];
  int t = threadIdx.x;
  int ol = t & 31, cs = t >> 5;
  int o = blockIdx.x * 32 + ol;
  float s = 0.f;
  #pragma unroll 16
  for (int c = cs * 16; c < cs * 16 + 16; ++c) s += part[(size_t)c * 8192 + o];
  sm[cs * 32 + ol] = s;
  __syncthreads();
  if (t < 32) {
    float tot = 0.f;
    #pragma unroll
    for (int j = 0; j < 8; ++j) tot += sm[j * 32 + t];
    int oo = blockIdx.x * 32 + t;
    float v = tot + blin[oo & 511];
    out[oo] = v / (1.f + __expf(-v));
  }
}

extern "C" void kernel_launch(void* const* d_in, const int* in_sizes, int n_in,
                              void* d_out, int out_size, void* d_ws, size_t ws_size,
                              hipStream_t stream) {
  const float* x   = (const float*)d_in[0];
  const float* WQ  = (const float*)d_in[1];
  const float* WK  = (const float*)d_in[2];
  const float* WV  = (const float*)d_in[3];
  const float* Wl  = (const float*)d_in[4];
  const float* bl  = (const float*)d_in[5];
  const float* lnw = (const float*)d_in[6];
  const float* lnb = (const float*)d_in[7];
  float* out = (float*)d_out;
  char* ws = (char*)d_ws;
  bfu* xb  = (bfu*)ws;                     // 4,194,304 bf16
  bfu* wt  = xb + 4194304;                 //   786,432 bf16
  bfu* qb  = wt + 786432;                  // 4,194,304 bf16
  bfu* kb  = qb + 4194304;                 // 4,194,304 bf16
  bfu* vtb = kb + 4194304;                 // 4,194,304 bf16
  float* attn = (float*)(vtb + 4194304);   // 4,194,304 f32
  bfu*   lno  = (bfu*)(attn + 4194304);    // 4,194,304 bf16
  float* part = (float*)(lno + 4194304);   // 1,048,576 f32

  k_prep    <<<4288, 256, 0, stream>>>(x, (uint2*)xb, WQ, WK, WV, wt);
  k_qkv     <<<dim3(64, 12), 256, 0, stream>>>(xb, wt, qb, kb, vtb);
  k_attn    <<<dim3(8, 8, 16), 256, 0, stream>>>(qb, kb, vtb, xb, attn);
  k_ln      <<<2048, 256, 0, stream>>>(attn, lnw, lnb, lno);
  k_lin_mfma<<<1024, 256, 0, stream>>>(lno, Wl, part);
  k_lin_red <<<256, 256, 0, stream>>>(part, bl, out);
}

// Round 16
// 176.499 us; speedup vs baseline: 1.0078x; 1.0078x over previous
//
#include <hip/hip_runtime.h>
#include <cstdint>

#define TB 16
#define TS 512
#define TD 512
#define TH 8
#define TDH 64
#define TSD (TS*TD)   // 262144

typedef __attribute__((ext_vector_type(8))) short s16x8;
typedef __attribute__((ext_vector_type(4))) float f32x4;
typedef unsigned short bfu;

// HW packed fp32->bf16 (RNE), gfx950
__device__ __forceinline__ unsigned cvt_pk(float lo, float hi) {
  unsigned r;
  asm("v_cvt_pk_bf16_f32 %0, %1, %2" : "=v"(r) : "v"(lo), "v"(hi));
  return r;
}
__device__ __forceinline__ unsigned short f2b(float f) {
  unsigned r;
  asm("v_cvt_pk_bf16_f32 %0, %1, %2" : "=v"(r) : "v"(f), "v"(f));
  return (unsigned short)r;
}
__device__ __forceinline__ float b2f(bfu h) {
  return __uint_as_float(((unsigned)h) << 16);
}

__device__ __forceinline__ void gll16(const void* g, void* l) {
  __builtin_amdgcn_global_load_lds((const __attribute__((address_space(1))) void*)g,
                                   (__attribute__((address_space(3))) void*)l, 16, 0, 0);
}

__device__ __forceinline__ f32x4 MFMA16(s16x8 a, s16x8 b, f32x4 c) {
  return __builtin_amdgcn_mfma_f32_16x16x32_bf16(a, b, c, 0, 0, 0);
}

// ---------------- K0: fused cast x (fp32->bf16) + build W^T bf16 [1536][512] ----------------
__global__ __launch_bounds__(256) void k_prep(const float* __restrict__ x, uint2* __restrict__ xb,
                                              const float* __restrict__ WQ, const float* __restrict__ WK,
                                              const float* __restrict__ WV, bfu* __restrict__ wt) {
  int t = threadIdx.x;
  if (blockIdx.x < 4096) {
    int i = blockIdx.x * 256 + t;
    float4 v = ((const float4*)x)[i];
    uint2 o; o.x = cvt_pk(v.x, v.y); o.y = cvt_pk(v.z, v.w);
    xb[i] = o;
    return;
  }
  __shared__ float tile[64][65];
  int bid = blockIdx.x - 4096;
  int bk = bid & 7;
  int bn = bid >> 3;
  const float* W = bn < 8 ? WQ : (bn < 16 ? WK : WV);
  int ncol0 = (bn & 7) * 64;
  int tx = t & 63, ty = t >> 6;
  #pragma unroll
  for (int i = 0; i < 16; ++i) {
    int kl = i * 4 + ty;
    tile[kl][tx] = W[(size_t)(bk * 64 + kl) * 512 + ncol0 + tx];
  }
  __syncthreads();
  #pragma unroll
  for (int i = 0; i < 16; ++i) {
    int nl = i * 4 + ty;
    wt[(size_t)(bn * 64 + nl) * 512 + bk * 64 + tx] = f2b(tile[tx][nl]);
  }
}

// ---------------- K1: QKV GEMM — round-7 proven: 256 thr, 4 waves, dbuf + swizzle ----------------
__global__ __launch_bounds__(256) void k_qkv(const bfu* __restrict__ xb, const bfu* __restrict__ wt,
                                             bfu* __restrict__ qb, bfu* __restrict__ kb, bfu* __restrict__ vtb) {
  __shared__ __align__(16) bfu At[2][128 * 32];
  __shared__ __align__(16) bfu Bt[2][128 * 32];
  int t = threadIdx.x, lane = t & 63, w = t >> 6;
  int wr = w >> 1, wc = w & 1;
  int m0 = blockIdx.x * 128, n0 = blockIdx.y * 128;
  int fr = lane & 15, hi = lane >> 4;
  int l4r = lane >> 2, l4c = lane & 3;
  f32x4 acc[4][4] = {};

#define QKV_STAGE(BUF, K0) { \
    _Pragma("unroll") \
    for (int i = 0; i < 2; ++i) { \
      int row = i * 64 + w * 16 + l4r; \
      int cs = l4c ^ (l4r & 3); \
      gll16(xb + (size_t)(m0 + row) * TD + (K0) + cs * 8, (char*)At[BUF] + (i * 256 + w * 64) * 16); \
      gll16(wt + (size_t)(n0 + row) * TD + (K0) + cs * 8, (char*)Bt[BUF] + (i * 256 + w * 64) * 16); \
    } }

#define QKV_COMP(BUF) { \
    s16x8 a[4], bb[4]; \
    int ca = (hi ^ (fr & 3)) * 8; \
    _Pragma("unroll") \
    for (int m = 0; m < 4; ++m) a[m]  = *(const s16x8*)&At[BUF][(wr * 64 + m * 16 + fr) * 32 + ca]; \
    _Pragma("unroll") \
    for (int n = 0; n < 4; ++n) bb[n] = *(const s16x8*)&Bt[BUF][(wc * 64 + n * 16 + fr) * 32 + ca]; \
    _Pragma("unroll") \
    for (int m = 0; m < 4; ++m) \
      _Pragma("unroll") \
      for (int n = 0; n < 4; ++n) \
        acc[m][n] = MFMA16(a[m], bb[n], acc[m][n]); }

  QKV_STAGE(0, 0)
  __syncthreads();
  for (int k = 0; k < 16; ++k) {
    int cur = k & 1;
    if (k < 15) QKV_STAGE(cur ^ 1, (k + 1) * 32)
    QKV_COMP(cur)
    __syncthreads();
  }
#undef QKV_STAGE
#undef QKV_COMP

  #pragma unroll
  for (int m = 0; m < 4; ++m) {
    int grow = m0 + wr * 64 + m * 16 + hi * 4;
    #pragma unroll
    for (int n = 0; n < 4; ++n) {
      int gcol = n0 + wc * 64 + n * 16 + fr;
      if (gcol < 512) {
        #pragma unroll
        for (int r = 0; r < 4; ++r) qb[(size_t)(grow + r) * TD + gcol] = f2b(acc[m][n][r]);
      } else if (gcol < 1024) {
        int c = gcol - 512;
        #pragma unroll
        for (int r = 0; r < 4; ++r) kb[(size_t)(grow + r) * TD + c] = f2b(acc[m][n][r]);
      } else {
        int c = gcol - 1024;
        int hh = c >> 6, dc = c & 63;
        int b_ = grow >> 9, s = grow & 511;
        ushort4 pk;
        pk.x = f2b(acc[m][n][0]); pk.y = f2b(acc[m][n][1]);
        pk.z = f2b(acc[m][n][2]); pk.w = f2b(acc[m][n][3]);
        *(ushort4*)&vtb[((size_t)((b_ * TH + hh) * TDH + dc) << 9) + s] = pk;
      }
    }
  }
}

// ---------------- K2: attention per (qtile=64, h, b) — Q in regs, 48KB LDS, bf16 out ----------------
__global__ __launch_bounds__(256) void k_attn(const bfu* __restrict__ qb, const bfu* __restrict__ kb,
                                              const bfu* __restrict__ vtb, const bfu* __restrict__ xb,
                                              bfu* __restrict__ ao) {
  __shared__ __align__(16) bfu Ks[128 * 64];
  __shared__ __align__(16) bfu Vs[64 * 128];
  __shared__ __align__(16) bfu Ps[64 * 128];
  int t = threadIdx.x, lane = t & 63, w = t >> 6;
  int qt = blockIdx.x, h = blockIdx.y, b = blockIdx.z;
  size_t qrow0 = (size_t)b * TS + qt * 64;
  int fr = lane & 15, hi = lane >> 4;
  int l8r = lane >> 3, l8c = lane & 7;
  int l16r = lane >> 4, l16c = lane & 15;

#define K_STAGE(KT) { \
    _Pragma("unroll") \
    for (int i = 0; i < 4; ++i) { \
      int row = i * 32 + w * 8 + l8r; \
      int cs = l8c ^ (l8r & 7); \
      gll16(kb + ((size_t)b * TS + (KT) * 128 + row) * TD + h * TDH + cs * 8, \
            (char*)Ks + (i * 256 + w * 64) * 16); \
    } }
#define V_STAGE(KT) { \
    _Pragma("unroll") \
    for (int i = 0; i < 4; ++i) { \
      int row = i * 16 + w * 4 + l16r; \
      int cs = l16c ^ (row & 7); \
      gll16(vtb + ((size_t)(b * TH + h) * TDH + row) * TS + (KT) * 128 + cs * 8, \
            (char*)Vs + (i * 256 + w * 64) * 16); \
    } }

  int qrow = w * 16 + fr;
  // Q fragments: loop-invariant, direct global->reg (qb is L2-hot)
  const bfu* qp = qb + (qrow0 + qrow) * TD + h * TDH;
  s16x8 aq0 = *(const s16x8*)(qp + hi * 8);
  s16x8 aq1 = *(const s16x8*)(qp + 32 + hi * 8);

  K_STAGE(0)
  V_STAGE(0)
  __syncthreads();

  int r7 = fr & 7;
  f32x4 acc_o[4] = {};
  for (int kt = 0; kt < 4; ++kt) {
    f32x4 sc[8];
    #pragma unroll
    for (int kj = 0; kj < 8; ++kj) {
      int krow = kj * 16 + fr;
      s16x8 b0 = *(const s16x8*)&Ks[krow * 64 + ((hi ^ r7) * 8)];
      s16x8 b1 = *(const s16x8*)&Ks[krow * 64 + (((4 + hi) ^ r7) * 8)];
      f32x4 c = {};
      c = MFMA16(aq0, b0, c);
      c = MFMA16(aq1, b1, c);
      sc[kj] = c;
    }
    #pragma unroll
    for (int kj = 0; kj < 8; ++kj) {
      #pragma unroll
      for (int r = 0; r < 4; ++r) {
        float v = sc[kj][r] * 0.125f;
        float p = v / (1.f + __expf(-v));
        int prow = w * 16 + hi * 4 + r;
        int c8 = (kj * 2 + (fr >> 3)) ^ (prow & 7);
        Ps[prow * 128 + c8 * 8 + (fr & 7)] = f2b(p);
      }
    }
    // P rows wave-private: same-wave LDS RAW covered by lgkmcnt; no barrier.
    #pragma unroll
    for (int ks = 0; ks < 4; ++ks) {
      s16x8 pa = *(const s16x8*)&Ps[qrow * 128 + (((ks * 4 + hi) ^ r7) * 8)];
      #pragma unroll
      for (int dn = 0; dn < 4; ++dn) {
        s16x8 vb = *(const s16x8*)&Vs[(dn * 16 + fr) * 128 + (((ks * 4 + hi) ^ r7) * 8)];
        acc_o[dn] = MFMA16(pa, vb, acc_o[dn]);
      }
    }
    __syncthreads();
    if (kt < 3) {
      K_STAGE(kt + 1)
      V_STAGE(kt + 1)
      __syncthreads();
    }
  }
#undef K_STAGE
#undef V_STAGE
  // epilogue: residual add in f32, store bf16 (halves attn->LN handoff traffic)
  #pragma unroll
  for (int dn = 0; dn < 4; ++dn) {
    int col = h * TDH + dn * 16 + fr;
    #pragma unroll
    for (int r = 0; r < 4; ++r) {
      size_t row = qrow0 + w * 16 + hi * 4 + r;
      ao[row * TD + col] = f2b(acc_o[dn][r] + b2f(xb[row * TD + col]));
    }
  }
}

// ---------------- K3: LayerNorm — wave-per-row, bf16 in/out, stats in f32 ----------------
__global__ __launch_bounds__(256) void k_ln(const bfu* __restrict__ a, const float* __restrict__ wgt,
                                            const float* __restrict__ bias, bfu* __restrict__ o) {
  int t = threadIdx.x, lane = t & 63, w = t >> 6;
  int row = blockIdx.x * 4 + w;
  const uint4* rp = (const uint4*)(a + (size_t)row * TD);
  uint4 u = rp[lane];                       // 8 bf16 at d = lane*8
  float v[8];
  v[0] = b2f((bfu)(u.x & 0xffff)); v[1] = b2f((bfu)(u.x >> 16));
  v[2] = b2f((bfu)(u.y & 0xffff)); v[3] = b2f((bfu)(u.y >> 16));
  v[4] = b2f((bfu)(u.z & 0xffff)); v[5] = b2f((bfu)(u.z >> 16));
  v[6] = b2f((bfu)(u.w & 0xffff)); v[7] = b2f((bfu)(u.w >> 16));
  float s = 0.f;
  #pragma unroll
  for (int i = 0; i < 8; ++i) s += v[i];
  #pragma unroll
  for (int off = 1; off < 64; off <<= 1) s += __shfl_xor(s, off);
  float mean = s * (1.f / 512.f);
  float q = 0.f;
  #pragma unroll
  for (int i = 0; i < 8; ++i) { float d = v[i] - mean; q += d * d; }
  #pragma unroll
  for (int off = 1; off < 64; off <<= 1) q += __shfl_xor(q, off);
  float inv = rsqrtf(q * (1.f / 512.f) + 1e-12f);
  float4 g0 = ((const float4*)wgt)[lane * 2],  g1 = ((const float4*)wgt)[lane * 2 + 1];
  float4 b0 = ((const float4*)bias)[lane * 2], b1 = ((const float4*)bias)[lane * 2 + 1];
  uint4 ov;
  ov.x = cvt_pk(fmaf((v[0] - mean) * inv, g0.x, b0.x), fmaf((v[1] - mean) * inv, g0.y, b0.y));
  ov.y = cvt_pk(fmaf((v[2] - mean) * inv, g0.z, b0.z), fmaf((v[3] - mean) * inv, g0.w, b0.w));
  ov.z = cvt_pk(fmaf((v[4] - mean) * inv, g1.x, b1.x), fmaf((v[5] - mean) * inv, g1.y, b1.y));
  ov.w = cvt_pk(fmaf((v[6] - mean) * inv, g1.z, b1.z), fmaf((v[7] - mean) * inv, g1.w, b1.w));
  ((uint4*)(o + (size_t)row * TD))[lane] = ov;
}

// ---------------- K4: final linear via MFMA — round-7 proven (KC=2048) ----------------
__global__ __launch_bounds__(256) void k_lin_mfma(const bfu* __restrict__ lno, const float* __restrict__ wl,
                                                  float* __restrict__ part) {
  __shared__ __align__(16) bfu Wt[2][64 * 72];
  int t = threadIdx.x, lane = t & 63, w = t >> 6;
  int fr = lane & 15, hi = lane >> 4;
  int kc = blockIdx.x >> 3, nb = blockIdx.x & 7;
  int n0 = nb * 64;
  int nl = t & 63, kb = (t >> 6) * 16;
  int ks0 = kc * 2048;
  const float* wbase = wl + (size_t)(ks0 + kb) * 512 + n0 + nl;
  const bfu*   abase = lno + (size_t)fr * TSD + ks0 + hi * 8;
  f32x4 acc = {};
  float wreg[16];
  #pragma unroll
  for (int i = 0; i < 16; ++i) wreg[i] = __builtin_nontemporal_load(wbase + (size_t)i * 512);
  for (int s = 0; s < 32; ++s) {
    int cur = s & 1;
    unsigned pk[8];
    #pragma unroll
    for (int i = 0; i < 8; ++i) pk[i] = cvt_pk(wreg[2 * i], wreg[2 * i + 1]);
    *(uint4*)&Wt[cur][nl * 72 + kb]     = *(uint4*)&pk[0];
    *(uint4*)&Wt[cur][nl * 72 + kb + 8] = *(uint4*)&pk[4];
    if (s < 31) {
      const float* wp2 = wbase + (size_t)(s + 1) * 64 * 512;
      #pragma unroll
      for (int i = 0; i < 16; ++i) wreg[i] = __builtin_nontemporal_load(wp2 + (size_t)i * 512);
    }
    s16x8 a0 = *(const s16x8*)(abase + s * 64);
    s16x8 a1 = *(const s16x8*)(abase + s * 64 + 32);
    __syncthreads();   // write(cur) visible; 2-buffer rotation + own-lgkmcnt => race-free
    s16x8 b0 = *(const s16x8*)&Wt[cur][(w * 16 + fr) * 72 + hi * 8];
    s16x8 b1 = *(const s16x8*)&Wt[cur][(w * 16 + fr) * 72 + 32 + hi * 8];
    acc = MFMA16(a0, b0, acc);
    acc = MFMA16(a1, b1, acc);
  }
  #pragma unroll
  for (int r = 0; r < 4; ++r)
    part[(size_t)kc * 8192 + (hi * 4 + r) * 512 + n0 + w * 16 + fr] = acc[r];
}

// ---------------- K5: reduce 128 partials + bias + swish — 256 blocks, 1 LDS hop ----------------
__global__ __launch_bounds__(256) void k_lin_red(const float* __restrict__ part, const float* __restrict__ blin,
                                                 float* __restrict__ out) {
  __shared__ float sm[256];
  int t = threadIdx.x;
  int ol = t & 31, cs = t >> 5;
  int o = blockIdx.x * 32 + ol;
  float s = 0.f;
  #pragma unroll 16
  for (int c = cs * 16; c < cs * 16 + 16; ++c) s += part[(size_t)c * 8192 + o];
  sm[cs * 32 + ol] = s;
  __syncthreads();
  if (t < 32) {
    float tot = 0.f;
    #pragma unroll
    for (int j = 0; j < 8; ++j) tot += sm[j * 32 + t];
    int oo = blockIdx.x * 32 + t;
    float v = tot + blin[oo & 511];
    out[oo] = v / (1.f + __expf(-v));
  }
}

extern "C" void kernel_launch(void* const* d_in, const int* in_sizes, int n_in,
                              void* d_out, int out_size, void* d_ws, size_t ws_size,
                              hipStream_t stream) {
  const float* x   = (const float*)d_in[0];
  const float* WQ  = (const float*)d_in[1];
  const float* WK  = (const float*)d_in[2];
  const float* WV  = (const float*)d_in[3];
  const float* Wl  = (const float*)d_in[4];
  const float* bl  = (const float*)d_in[5];
  const float* lnw = (const float*)d_in[6];
  const float* lnb = (const float*)d_in[7];
  float* out = (float*)d_out;
  char* ws = (char*)d_ws;
  bfu* xb  = (bfu*)ws;                     // 4,194,304 bf16
  bfu* wt  = xb + 4194304;                 //   786,432 bf16
  bfu* qb  = wt + 786432;                  // 4,194,304 bf16
  bfu* kb  = qb + 4194304;                 // 4,194,304 bf16
  bfu* vtb = kb + 4194304;                 // 4,194,304 bf16
  bfu* ao  = vtb + 4194304;                // 4,194,304 bf16
  bfu* lno = ao + 4194304;                 // 4,194,304 bf16
  float* part = (float*)(lno + 4194304);   // 1,048,576 f32

  k_prep    <<<4288, 256, 0, stream>>>(x, (uint2*)xb, WQ, WK, WV, wt);
  k_qkv     <<<dim3(64, 12), 256, 0, stream>>>(xb, wt, qb, kb, vtb);
  k_attn    <<<dim3(8, 8, 16), 256, 0, stream>>>(qb, kb, vtb, xb, ao);
  k_ln      <<<2048, 256, 0, stream>>>(ao, lnw, lnb, lno);
  k_lin_mfma<<<1024, 256, 0, stream>>>(lno, Wl, part);
  k_lin_red <<<256, 256, 0, stream>>>(part, bl, out);
}